// Round 1
// baseline (279.264 us; speedup 1.0000x reference)
//
#include <hip/hip_runtime.h>
#include <hip/hip_bf16.h>

typedef unsigned short u16;
typedef short s16x8 __attribute__((ext_vector_type(8)));
typedef float f32x4 __attribute__((ext_vector_type(4)));

#define NB 8
#define NT 2048
#define NC 512
#define NH 512

__device__ __forceinline__ u16 f2bf(float f) {
  unsigned u = __float_as_uint(f);
  u += 0x7FFFu + ((u >> 16) & 1u);   // round-to-nearest-even
  return (u16)(u >> 16);
}

// ---------------- K0: W [C][H] fp32 -> WT [H][C] bf16 ----------------
__global__ __launch_bounds__(256) void wt_kernel(const float* __restrict__ W,
                                                 u16* __restrict__ WT) {
  __shared__ float tile[32][33];
  const int x = threadIdx.x & 31;
  const int y = threadIdx.x >> 5;
  const int k0 = blockIdx.x * 32, h0 = blockIdx.y * 32;
#pragma unroll
  for (int p = 0; p < 4; ++p)
    tile[y + 8 * p][x] = W[(size_t)(k0 + y + 8 * p) * NH + h0 + x];
  __syncthreads();
#pragma unroll
  for (int p = 0; p < 4; ++p)
    WT[(size_t)(h0 + y + 8 * p) * NC + k0 + x] = f2bf(tile[x][y + 8 * p]);
}

// ---------------- K1: Y = X @ W + b   (X fp32 [M][512], WT bf16 [N][K], Y bf16) ----
// grid (4, 128), block 256 (4 waves). BM=BN=128, BK=32.
__global__ __launch_bounds__(256) void proj_kernel(const float* __restrict__ X,
                                                   const u16* __restrict__ WT,
                                                   const float* __restrict__ bias,
                                                   u16* __restrict__ Y) {
  __shared__ __align__(16) u16 Asub[128 * 40];
  __shared__ __align__(16) u16 Bsub[128 * 40];
  const int t = threadIdx.x;
  const int lane = t & 63;
  const int w = t >> 6;
  const int l16 = lane & 15;
  const int ko8 = (lane >> 4) * 8;
  const int m0 = blockIdx.y * 128;
  const int n0 = blockIdx.x * 128;
  const int wr = (w >> 1) * 64, wc = (w & 1) * 64;
  f32x4 acc[4][4] = {};

  for (int kt = 0; kt < 16; ++kt) {
    const int k0 = kt * 32;
    // stage A: 128 rows x 32 fp32 -> bf16 LDS (padded stride 40)
#pragma unroll
    for (int p = 0; p < 4; ++p) {
      int c = t + 256 * p;                 // 1024 float4 chunks
      int r = c >> 3, cc = (c & 7) * 4;
      const float4 v = *(const float4*)&X[(size_t)(m0 + r) * NC + k0 + cc];
      ushort4 bb;
      bb.x = f2bf(v.x); bb.y = f2bf(v.y); bb.z = f2bf(v.z); bb.w = f2bf(v.w);
      *(ushort4*)&Asub[r * 40 + cc] = bb;
    }
    // stage B: 128 rows x 32 bf16 (already bf16 in ws)
#pragma unroll
    for (int p = 0; p < 2; ++p) {
      int c = t + 256 * p;                 // 512 16B chunks
      int r = c >> 2, cc = (c & 3) * 8;
      *(int4*)&Bsub[r * 40 + cc] = *(const int4*)&WT[(size_t)(n0 + r) * NC + k0 + cc];
    }
    __syncthreads();
    s16x8 af[4], bf[4];
#pragma unroll
    for (int i = 0; i < 4; ++i)
      af[i] = *(const s16x8*)&Asub[(wr + i * 16 + l16) * 40 + ko8];
#pragma unroll
    for (int j = 0; j < 4; ++j)
      bf[j] = *(const s16x8*)&Bsub[(wc + j * 16 + l16) * 40 + ko8];
#pragma unroll
    for (int i = 0; i < 4; ++i)
#pragma unroll
      for (int j = 0; j < 4; ++j)
        acc[i][j] = __builtin_amdgcn_mfma_f32_16x16x32_bf16(af[i], bf[j], acc[i][j], 0, 0, 0);
    __syncthreads();
  }
  // epilogue: += bias, convert to bf16, store
  const int rg = (lane >> 4) * 4;
#pragma unroll
  for (int i = 0; i < 4; ++i)
#pragma unroll
    for (int j = 0; j < 4; ++j) {
      const int col = n0 + wc + j * 16 + l16;
      const float bcol = bias[col];
#pragma unroll
      for (int jj = 0; jj < 4; ++jj) {
        const int row = m0 + wr + i * 16 + rg + jj;
        Y[(size_t)row * NH + col] = f2bf(acc[i][j][jj] + bcol);
      }
    }
}

// ---------------- K2: Vp [B][T][H] bf16 -> VpT [B][H][T] bf16 ----------------
__global__ __launch_bounds__(256) void vt_kernel(const u16* __restrict__ Vp,
                                                 u16* __restrict__ VpT) {
  __shared__ u16 tile[32][33];
  const int x = threadIdx.x & 31;
  const int y = threadIdx.x >> 5;
  const int t0 = blockIdx.x * 32, h0 = blockIdx.y * 32, b = blockIdx.z;
  const u16* src = Vp + (size_t)b * NT * NH;
  u16* dst = VpT + (size_t)b * NH * NT;
#pragma unroll
  for (int p = 0; p < 4; ++p)
    tile[y + 8 * p][x] = src[(size_t)(t0 + y + 8 * p) * NH + h0 + x];
  __syncthreads();
#pragma unroll
  for (int p = 0; p < 4; ++p)
    dst[(size_t)(h0 + y + 8 * p) * NT + t0 + x] = tile[x][y + 8 * p];
}

// ---------------- K3: flash attention ----------------
// grid (B=8, T/64=32)  [batch on x so round-robin XCD assignment ~= batch->XCD]
// block 512 (8 waves). QB=64 rows per block, KB=32 per iteration, D=H=512.
__global__ __launch_bounds__(512, 2) void flash_kernel(const u16* __restrict__ Qp,
                                                       const u16* __restrict__ Kp,
                                                       const u16* __restrict__ VpT,
                                                       float* __restrict__ out) {
  __shared__ __align__(16) u16 Klds[32 * 520];   // [kv][feat], pad 8
  __shared__ __align__(16) u16 Vlds[512 * 40];   // [h][kv], pad 8
  __shared__ __align__(16) float Slds[64 * 33];  // [qrow][kv]
  __shared__ __align__(16) u16 Plds[64 * 40];    // [qrow][kv] bf16
  __shared__ float red[64 * 9];
  __shared__ float m_s[64], l_s[64], sc_s[64];

  const int t = threadIdx.x;
  const int lane = t & 63;
  const int w = t >> 6;
  const int l16 = lane & 15;
  const int ko8 = (lane >> 4) * 8;
  const int b = blockIdx.x;
  const int q0 = blockIdx.y * 64;
  const int rb = w >> 1;  // S rowblock 0..3
  const int cb = w & 1;   // S colblock 0..1
  const float kscale = 0.044194173824159216f;  // 1/sqrt(512)

  // Q fragments for this wave's S rows (q0 + rb*16 + l16), all 512 features
  s16x8 qf[16];
  {
    const u16* qrow = Qp + (size_t)(b * NT + q0 + rb * 16 + l16) * NH;
#pragma unroll
    for (int ks = 0; ks < 16; ++ks)
      qf[ks] = *(const s16x8*)&qrow[ks * 32 + ko8];
  }
  f32x4 oacc[4][4] = {};  // [qrow block 0..3][h block 0..3], h slice = w*64..+64
  if (t < 64) { m_s[t] = -INFINITY; l_s[t] = 0.f; }
  __syncthreads();

  for (int it = 0; it < 64; ++it) {
    const int kv0 = it * 32;
    // stage K tile [32][512] and V^T tile [512][32]
    {
      const u16* kbase = Kp + (size_t)(b * NT + kv0) * NH;
#pragma unroll
      for (int p = 0; p < 4; ++p) {
        int c = t + 512 * p;               // 2048 chunks
        int r = c >> 6, cc = (c & 63) * 8;
        *(int4*)&Klds[r * 520 + cc] = *(const int4*)&kbase[(size_t)r * NH + cc];
      }
      const u16* vbase = VpT + (size_t)b * NH * NT + kv0;
#pragma unroll
      for (int p = 0; p < 4; ++p) {
        int c = t + 512 * p;               // 2048 chunks
        int h = c >> 2, cc = (c & 3) * 8;
        *(int4*)&Vlds[h * 40 + cc] = *(const int4*)&vbase[(size_t)h * NT + cc];
      }
    }
    __syncthreads();
    // S = Q K^T * kscale  (each wave one 16x16 tile of the 64x32 S)
    {
      f32x4 sacc = {};
#pragma unroll
      for (int ks = 0; ks < 16; ++ks) {
        s16x8 kf = *(const s16x8*)&Klds[(cb * 16 + l16) * 520 + ks * 32 + ko8];
        sacc = __builtin_amdgcn_mfma_f32_16x16x32_bf16(qf[ks], kf, sacc, 0, 0, 0);
      }
      const int r0 = rb * 16 + (lane >> 4) * 4;
      const int ccol = cb * 16 + l16;
#pragma unroll
      for (int j = 0; j < 4; ++j)
        Slds[(r0 + j) * 33 + ccol] = sacc[j] * kscale;
    }
    __syncthreads();
    // rowwise partial max (8 groups x 4 cols)
    {
      const int r = t & 63, g = t >> 6;
      const float* srow = &Slds[r * 33 + g * 4];
      red[r * 9 + g] = fmaxf(fmaxf(srow[0], srow[1]), fmaxf(srow[2], srow[3]));
    }
    __syncthreads();
    if (t < 64) {
      float mt = red[t * 9];
#pragma unroll
      for (int g = 1; g < 8; ++g) mt = fmaxf(mt, red[t * 9 + g]);
      const float mold = m_s[t];
      const float mnew = fmaxf(mold, mt);
      sc_s[t] = __expf(mold - mnew);
      m_s[t] = mnew;
    }
    __syncthreads();
    // P = exp(S - m) -> bf16, partial sums
    {
      const int r = t & 63, g = t >> 6;
      const float mnew = m_s[r];
      float s = 0.f;
#pragma unroll
      for (int c4 = 0; c4 < 4; ++c4) {
        const int c = g * 4 + c4;
        const float e = __expf(Slds[r * 33 + c] - mnew);
        Plds[r * 40 + c] = f2bf(e);
        s += e;
      }
      red[r * 9 + g] = s;
    }
    __syncthreads();
    if (t < 64) {
      float s = 0.f;
#pragma unroll
      for (int g = 0; g < 8; ++g) s += red[t * 9 + g];
      l_s[t] = l_s[t] * sc_s[t] + s;
    }
    // O rescale + PV (oacc += P @ V, this wave's 64-col h slice)
    {
#pragma unroll
      for (int i = 0; i < 4; ++i) {
        const int r0 = i * 16 + (lane >> 4) * 4;
        const float s0 = sc_s[r0], s1 = sc_s[r0 + 1], s2 = sc_s[r0 + 2], s3 = sc_s[r0 + 3];
#pragma unroll
        for (int j = 0; j < 4; ++j) {
          oacc[i][j][0] *= s0; oacc[i][j][1] *= s1;
          oacc[i][j][2] *= s2; oacc[i][j][3] *= s3;
        }
      }
      s16x8 pf[4], vf[4];
#pragma unroll
      for (int i = 0; i < 4; ++i)
        pf[i] = *(const s16x8*)&Plds[(i * 16 + l16) * 40 + ko8];
#pragma unroll
      for (int j = 0; j < 4; ++j)
        vf[j] = *(const s16x8*)&Vlds[(w * 64 + j * 16 + l16) * 40 + ko8];
#pragma unroll
      for (int i = 0; i < 4; ++i)
#pragma unroll
        for (int j = 0; j < 4; ++j)
          oacc[i][j] = __builtin_amdgcn_mfma_f32_16x16x32_bf16(pf[i], vf[j], oacc[i][j], 0, 0, 0);
    }
    __syncthreads();
  }
  // epilogue: O /= l, store fp32
#pragma unroll
  for (int i = 0; i < 4; ++i) {
    const int r0 = i * 16 + (lane >> 4) * 4;
    const float i0 = 1.f / l_s[r0], i1 = 1.f / l_s[r0 + 1];
    const float i2 = 1.f / l_s[r0 + 2], i3 = 1.f / l_s[r0 + 3];
#pragma unroll
    for (int j = 0; j < 4; ++j) {
      const int col = w * 64 + j * 16 + l16;
      float* obase = out + (size_t)(b * NT + q0 + r0) * NH + col;
      obase[0 * NH] = oacc[i][j][0] * i0;
      obase[1 * NH] = oacc[i][j][1] * i1;
      obase[2 * NH] = oacc[i][j][2] * i2;
      obase[3 * NH] = oacc[i][j][3] * i3;
    }
  }
}

extern "C" void kernel_launch(void* const* d_in, const int* in_sizes, int n_in,
                              void* d_out, int out_size, void* d_ws, size_t ws_size,
                              hipStream_t stream) {
  (void)in_sizes; (void)n_in; (void)out_size; (void)ws_size;
  const float* q  = (const float*)d_in[0];
  const float* k  = (const float*)d_in[1];
  const float* v  = (const float*)d_in[2];
  const float* Wq = (const float*)d_in[3];
  const float* bq = (const float*)d_in[4];
  const float* Wk = (const float*)d_in[5];
  const float* bk = (const float*)d_in[6];
  const float* Wv = (const float*)d_in[7];
  const float* bv = (const float*)d_in[8];
  float* out = (float*)d_out;

  u16* ws   = (u16*)d_ws;
  u16* WqT  = ws;                       // 512*512
  u16* WkT  = WqT + (size_t)NC * NH;
  u16* WvT  = WkT + (size_t)NC * NH;
  u16* Qp   = WvT + (size_t)NC * NH;    // B*T*H each
  u16* Kp   = Qp + (size_t)NB * NT * NH;
  u16* Vp   = Kp + (size_t)NB * NT * NH;
  u16* VpT  = Vp + (size_t)NB * NT * NH;

  wt_kernel<<<dim3(16, 16), 256, 0, stream>>>(Wq, WqT);
  wt_kernel<<<dim3(16, 16), 256, 0, stream>>>(Wk, WkT);
  wt_kernel<<<dim3(16, 16), 256, 0, stream>>>(Wv, WvT);

  proj_kernel<<<dim3(4, 128), 256, 0, stream>>>(q, WqT, bq, Qp);
  proj_kernel<<<dim3(4, 128), 256, 0, stream>>>(k, WkT, bk, Kp);
  proj_kernel<<<dim3(4, 128), 256, 0, stream>>>(v, WvT, bv, Vp);

  vt_kernel<<<dim3(64, 16, NB), 256, 0, stream>>>(Vp, VpT);

  flash_kernel<<<dim3(NB, NT / 64), 512, 0, stream>>>(Qp, Kp, VpT, out);
}